// Round 1
// baseline (9199.786 us; speedup 1.0000x reference)
//
#include <hip/hip_runtime.h>
#include <hip/hip_bf16.h>
#include <cstdint>
#include <cstddef>

// ============================================================================
// EchoStateNetwork: h_{t+1} = 0.5*tanh([h_t ; x_t] @ [[W];[Wi^T]]) + 0.5*h_t
// Persistent-kernel scan, 128 WGs, custom grid barrier, W in VGPRs.
//
// ws layout (bytes):
//   Whi  [1024 n][1280 k] bf16  : W (k<1024) and bf16(Wi) (k>=1024)   2,621,440
//   Wlo  [1024 n][ 256 j] bf16  : Wi residual (Wi - bf16(Wi))           524,288
//   Xhi  [512 t][32 b][256 j]   : bf16(x)                             8,388,608
//   Xlo  [512 t][32 b][256 j]   : x residual                          8,388,608
//   Hb   [2][128 row][1024] bf16: double-buffered shared state          524,288
//   bar  [arrive, release] u32                                              256
// total ~20.4 MB
// ============================================================================

typedef unsigned short u16;
typedef unsigned int   u32;
typedef unsigned long long u64;
typedef __bf16 bf16x8 __attribute__((ext_vector_type(8)));
typedef float  f32x4  __attribute__((ext_vector_type(4)));

#define T_STEPS 512
#define R_DIM   1024
#define KX      256
#define K_TOT   1280
#define NROWS   128
#define NWG     128
#define TPB     256

#define OFF_WHI  0
#define OFF_WLO  (OFF_WHI + 1024*1280*2)
#define OFF_XHI  (OFF_WLO + 1024*256*2)
#define OFF_XLO  (OFF_XHI + 512*32*256*2)
#define OFF_HB   (OFF_XLO + 512*32*256*2)
#define OFF_BAR  (OFF_HB  + 2*128*1024*2)

__device__ __forceinline__ u16 f2bf(float f) {
  u32 u = __builtin_bit_cast(u32, f);
  u += 0x7fffu + ((u >> 16) & 1u);          // RNE
  return (u16)(u >> 16);
}
__device__ __forceinline__ float bf2f(u16 h) {
  u32 u = ((u32)h) << 16;
  return __builtin_bit_cast(float, u);
}

// --- prep: Whi/Wlo ----------------------------------------------------------
__global__ void prep_w(const float* __restrict__ W, const float* __restrict__ Wi,
                       u16* __restrict__ whi, u16* __restrict__ wlo) {
  int n = blockIdx.y;
  int k = blockIdx.x * 256 + threadIdx.x;   // 0..1279
  if (k < 1024) {
    whi[n * K_TOT + k] = f2bf(W[k * 1024 + n]);
  } else {
    float v = Wi[n * 256 + (k - 1024)];
    u16 hi = f2bf(v);
    whi[n * K_TOT + k] = hi;
    wlo[n * 256 + (k - 1024)] = f2bf(v - bf2f(hi));
  }
}

// --- prep: Xhi/Xlo  (x[B,C,T,I] -> [T][B][C*I] split hi/lo) ----------------
__global__ void prep_x(const float* __restrict__ x,
                       u16* __restrict__ xhi, u16* __restrict__ xlo) {
  int t = blockIdx.x, b = blockIdx.y, j = threadIdx.x;   // j = c*64+i
  float v = x[(size_t)(((b << 2) | (j >> 6)) * 512 + t) * 64 + (j & 63)];
  u16 hi = f2bf(v);
  int o = t * 8192 + b * 256 + j;
  xhi[o] = hi;
  xlo[o] = f2bf(v - bf2f(hi));
}

// --- the scan ---------------------------------------------------------------
__global__ void __launch_bounds__(TPB, 1) esn_scan(
    const u16* __restrict__ Whi, const u16* __restrict__ Wlo,
    const u16* __restrict__ Xhi, const u16* __restrict__ Xlo,
    u16* __restrict__ Hb, float* __restrict__ out, u32* __restrict__ bar) {
  // LDS: h rows [16][1024] bf16 (xor-swizzled) + xhi[4][256] + xlo[4][256]
  __shared__ __align__(16) u16 smem[16 * 1024 + 2 * 4 * 256];
  char* smb = (char*)smem;

  const int wg   = blockIdx.x;
  const int cs   = ((wg & 7) << 1) | ((wg >> 3) & 1);  // col-slice, XCD-affine guess
  const int rg   = wg >> 4;                            // row-group 0..7
  const int tid  = threadIdx.x;
  const int wave = tid >> 6;
  const int lane = tid & 63;
  const int m    = lane & 15;   // A-row / B-col / D-col index
  const int kb   = lane >> 4;   // k-block 0..3
  const int row0 = rg << 4;
  const int b0   = row0 >> 2;
  const int n0   = (cs << 6) + (wave << 4);

  // ---- preload this wave's W fragments into registers (stay live all T) ----
  // B frag (16x16x32): lane holds B[k0 + kb*8 + e][n0 + m], e=0..7 contiguous
  const char* bbase = (const char*)Whi + (size_t)(n0 + m) * K_TOT * 2;
  const char* lbase = (const char*)Wlo + (size_t)(n0 + m) * KX * 2;
  bf16x8 bh_reg[40];
  bf16x8 bl_reg[8];
#pragma unroll
  for (int kt = 0; kt < 40; ++kt)
    bh_reg[kt] = *(const bf16x8*)(bbase + (kt << 6) + (kb << 4));
#pragma unroll
  for (int kt = 0; kt < 8; ++kt)
    bl_reg[kt] = *(const bf16x8*)(lbase + (kt << 6) + (kb << 4));

  // x-staging targets (per-thread constants)
  const int xhalf = tid >> 7;          // 0=hi 1=lo
  const int xt_   = tid & 127;
  const int xbl   = xt_ >> 5;          // 0..3 (local b)
  const int xcolb = (xt_ & 31) << 4;   // 0..496
  char* xdst = smb + 32768 + xhalf * 2048 + xbl * 512 + (xcolb ^ ((xbl & 3) << 4));

  float hreg[4] = {0.f, 0.f, 0.f, 0.f};   // fp32 leak state (h0 = 0)

  for (int t = 0; t < T_STEPS; ++t) {
    const u16* Hcur  = Hb + (size_t)(t & 1) * (NROWS * R_DIM);
    u16*       Hnext = Hb + (size_t)((t + 1) & 1) * (NROWS * R_DIM);

    // ---- stage h rows (agent-coherent loads: written by other XCDs) ----
    {
      u64* src = (u64*)(Hcur + row0 * R_DIM);
#pragma unroll
      for (int it = 0; it < 16; ++it) {   // one 2KB row per iteration
        u64 v = __hip_atomic_load(src + it * 256 + tid,
                                  __ATOMIC_RELAXED, __HIP_MEMORY_SCOPE_AGENT);
        *(u64*)(smb + it * 2048 + ((tid * 8) ^ ((it & 7) << 4))) = v;
      }
      // stage x hi/lo slices (read-only data: normal loads)
      const u16* xs = (xhalf ? Xlo : Xhi) + (size_t)t * 8192 + (b0 + xbl) * 256;
      uint4 xv = *(const uint4*)((const char*)xs + xcolb);
      *(uint4*)xdst = xv;
    }
    __syncthreads();

    // ---- z = [h ; xhi+xlo] @ [W ; Wihi+Wilo] -------------------------------
    f32x4 acc = {0.f, 0.f, 0.f, 0.f};
#pragma unroll 4
    for (int kt = 0; kt < 32; ++kt) {     // h part, plain bf16
      int colb = (kt << 6) + (kb << 4);
      bf16x8 a = *(const bf16x8*)(smb + m * 2048 + (colb ^ ((m & 7) << 4)));
      acc = __builtin_amdgcn_mfma_f32_16x16x32_bf16(a, bh_reg[kt], acc, 0, 0, 0);
    }
    {
      const char* xbh = smb + 32768 + (m >> 2) * 512;
      const char* xbl16 = xbh + 2048;
#pragma unroll 2
      for (int kt = 0; kt < 8; ++kt) {    // input part, hi/lo split (3 terms)
        int colb = (kt << 6) + (kb << 4);
        int sco  = colb ^ (((m >> 2) & 3) << 4);
        bf16x8 axh = *(const bf16x8*)(xbh + sco);
        bf16x8 axl = *(const bf16x8*)(xbl16 + sco);
        acc = __builtin_amdgcn_mfma_f32_16x16x32_bf16(axh, bh_reg[32 + kt], acc, 0, 0, 0);
        acc = __builtin_amdgcn_mfma_f32_16x16x32_bf16(axh, bl_reg[kt],      acc, 0, 0, 0);
        acc = __builtin_amdgcn_mfma_f32_16x16x32_bf16(axl, bh_reg[32 + kt], acc, 0, 0, 0);
      }
    }

    // ---- epilogue: D[row=(kb*4+r)][col=m]; leak in fp32 --------------------
#pragma unroll
    for (int r = 0; r < 4; ++r) {
      int grow = row0 + (kb << 2) + r;
      int gcol = n0 + m;
      float hn = 0.5f * tanhf(acc[r]) + 0.5f * hreg[r];
      hreg[r] = hn;
      Hnext[grow * R_DIM + gcol] = f2bf(hn);
      out[((size_t)grow * T_STEPS + t) * R_DIM + gcol] = hn;
    }

    // ---- grid barrier (monotonic counter + release generation) -------------
    __syncthreads();
    if (t < T_STEPS - 1) {
      if (tid == 0) {
        __threadfence();  // wbL2: make Hnext visible at coherence point
        u32 prev = __hip_atomic_fetch_add(bar, 1u,
                        __ATOMIC_RELAXED, __HIP_MEMORY_SCOPE_AGENT);
        if (prev == (u32)NWG * (u32)(t + 1) - 1u) {
          __hip_atomic_store(bar + 1, (u32)(t + 1),
                             __ATOMIC_RELAXED, __HIP_MEMORY_SCOPE_AGENT);
        } else {
          while (__hip_atomic_load(bar + 1, __ATOMIC_RELAXED,
                                   __HIP_MEMORY_SCOPE_AGENT) < (u32)(t + 1)) {
            __builtin_amdgcn_s_sleep(2);
          }
        }
      }
      __syncthreads();
    }
  }
}

// ============================================================================
extern "C" void kernel_launch(void* const* d_in, const int* in_sizes, int n_in,
                              void* d_out, int out_size, void* d_ws, size_t ws_size,
                              hipStream_t stream) {
  (void)in_sizes; (void)n_in; (void)out_size; (void)ws_size;
  const float* x  = (const float*)d_in[0];   // [32,4,512,64]
  const float* Wi = (const float*)d_in[1];   // [1024,256]
  const float* W  = (const float*)d_in[2];   // [1024,1024]
  float* out = (float*)d_out;                // [32,4,512,1024]

  char* ws  = (char*)d_ws;
  u16*  whi = (u16*)(ws + OFF_WHI);
  u16*  wlo = (u16*)(ws + OFF_WLO);
  u16*  xhi = (u16*)(ws + OFF_XHI);
  u16*  xlo = (u16*)(ws + OFF_XLO);
  u16*  hb  = (u16*)(ws + OFF_HB);
  u32*  bar = (u32*)(ws + OFF_BAR);

  // zero h0 double-buffer + barrier state (ws is poisoned, not re-poisoned)
  hipMemsetAsync(ws + OFF_HB, 0, 2 * 128 * 1024 * 2 + 256, stream);

  hipLaunchKernelGGL(prep_w, dim3(5, 1024), dim3(256), 0, stream, W, Wi, whi, wlo);
  hipLaunchKernelGGL(prep_x, dim3(512, 32), dim3(256), 0, stream, x, xhi, xlo);
  hipLaunchKernelGGL(esn_scan, dim3(NWG), dim3(TPB), 0, stream,
                     whi, wlo, xhi, xlo, hb, out, bar);
}

// Round 4
// 6609.729 us; speedup vs baseline: 1.3919x; 1.3919x over previous
//
#include <hip/hip_runtime.h>
#include <hip/hip_bf16.h>
#include <cstdint>
#include <cstddef>

// ============================================================================
// EchoStateNetwork: h_{t+1} = 0.5*tanh([h_t ; x_t] @ [[W];[Wi^T]]) + 0.5*h_t
// Persistent 128-WG scan. R1-proven exchange protocol: plain Hnext stores +
// per-WG __threadfence() (wbl2) + relaxed agent atomic loads into LDS.
// R4 deltas: W pinned in VGPRs (asm "+v"), nt stores for out[], 8-way split
// arrive counter. Nothing else touched.
//
// ws layout (bytes):
//   Whi  [1024 n][1280 k] bf16  : W (k<1024) and bf16(Wi) (k>=1024)   2,621,440
//   Wlo  [1024 n][ 256 j] bf16  : Wi residual                           524,288
//   Xhi  [512 t][32 b][256 j]   : bf16(x)                             8,388,608
//   Xlo  [512 t][32 b][256 j]   : x residual                          8,388,608
//   Hb   [2][128 row][1024] bf16: double-buffered shared state          524,288
//   bar  arrive[8] (256B apart) + done + release                          4,096
// ============================================================================

typedef unsigned short u16;
typedef unsigned int   u32;
typedef unsigned long long u64;
typedef __bf16 bf16x8 __attribute__((ext_vector_type(8)));
typedef float  f32x4  __attribute__((ext_vector_type(4)));

#define T_STEPS 512
#define R_DIM   1024
#define KX      256
#define K_TOT   1280
#define NROWS   128
#define NWG     128
#define TPB     256

#define OFF_WHI  0
#define OFF_WLO  (OFF_WHI + 1024*1280*2)
#define OFF_XHI  (OFF_WLO + 1024*256*2)
#define OFF_XLO  (OFF_XHI + 512*32*256*2)
#define OFF_HB   (OFF_XLO + 512*32*256*2)
#define OFF_BAR  (OFF_HB  + 2*128*1024*2)

__device__ __forceinline__ u16 f2bf(float f) {
  u32 u = __builtin_bit_cast(u32, f);
  u += 0x7fffu + ((u >> 16) & 1u);          // RNE
  return (u16)(u >> 16);
}
__device__ __forceinline__ float bf2f(u16 h) {
  u32 u = ((u32)h) << 16;
  return __builtin_bit_cast(float, u);
}
__device__ __forceinline__ void pinv(bf16x8& v) { asm volatile("" : "+v"(v)); }

// --- prep: Whi/Wlo ----------------------------------------------------------
__global__ void prep_w(const float* __restrict__ W, const float* __restrict__ Wi,
                       u16* __restrict__ whi, u16* __restrict__ wlo) {
  int n = blockIdx.y;
  int k = blockIdx.x * 256 + threadIdx.x;   // 0..1279
  if (k < 1024) {
    whi[n * K_TOT + k] = f2bf(W[k * 1024 + n]);
  } else {
    float v = Wi[n * 256 + (k - 1024)];
    u16 hi = f2bf(v);
    whi[n * K_TOT + k] = hi;
    wlo[n * 256 + (k - 1024)] = f2bf(v - bf2f(hi));
  }
}

// --- prep: Xhi/Xlo  (x[B,C,T,I] -> [T][B][C*I] split hi/lo) ----------------
__global__ void prep_x(const float* __restrict__ x,
                       u16* __restrict__ xhi, u16* __restrict__ xlo) {
  int t = blockIdx.x, b = blockIdx.y, j = threadIdx.x;   // j = c*64+i
  float v = x[(size_t)(((b << 2) | (j >> 6)) * 512 + t) * 64 + (j & 63)];
  u16 hi = f2bf(v);
  int o = t * 8192 + b * 256 + j;
  xhi[o] = hi;
  xlo[o] = f2bf(v - bf2f(hi));
}

// --- the scan ---------------------------------------------------------------
__global__ void __launch_bounds__(TPB, 1) esn_scan(
    const u16* __restrict__ Whi, const u16* __restrict__ Wlo,
    const u16* __restrict__ Xhi, const u16* __restrict__ Xlo,
    u16* __restrict__ Hb, float* __restrict__ out, u32* __restrict__ bar) {
  // LDS: h rows [16][1024] bf16 (xor-swizzled) + xhi[4][256] + xlo[4][256]
  __shared__ __align__(16) u16 smem[16 * 1024 + 2 * 4 * 256];
  char* smb = (char*)smem;

  const int wg   = blockIdx.x;
  const int cs   = ((wg & 7) << 1) | ((wg >> 3) & 1);  // col-slice
  const int rg   = wg >> 4;                            // row-group 0..7
  const int tid  = threadIdx.x;
  const int wave = tid >> 6;
  const int lane = tid & 63;
  const int m    = lane & 15;   // A-row / B-col / D-col index
  const int kb   = lane >> 4;   // k-block 0..3
  const int row0 = rg << 4;
  const int b0   = row0 >> 2;
  const int n0   = (cs << 6) + (wave << 4);

  // ---- preload this wave's W fragments into registers, PIN them -----------
  // B frag (16x16x32): lane holds B[k0 + kb*8 + e][n0 + m], e=0..7 contiguous
  const char* bbase = (const char*)Whi + (size_t)(n0 + m) * K_TOT * 2;
  const char* lbase = (const char*)Wlo + (size_t)(n0 + m) * KX * 2;
  bf16x8 bh[40];
  bf16x8 bl[8];
#pragma unroll
  for (int kt = 0; kt < 40; ++kt)
    bh[kt] = *(const bf16x8*)(bbase + (kt << 6) + (kb << 4));
#pragma unroll
  for (int kt = 0; kt < 8; ++kt)
    bl[kt] = *(const bf16x8*)(lbase + (kt << 6) + (kb << 4));
#pragma unroll
  for (int kt = 0; kt < 40; ++kt) pinv(bh[kt]);
#pragma unroll
  for (int kt = 0; kt < 8; ++kt) pinv(bl[kt]);

  // x-staging targets (per-thread constants)
  const int xhalf = tid >> 7;          // 0=hi 1=lo
  const int xt_   = tid & 127;
  const int xbl   = xt_ >> 5;          // 0..3 (local b)
  const int xcolb = (xt_ & 31) << 4;   // 0..496
  char* xdst = smb + 32768 + xhalf * 2048 + xbl * 512 + (xcolb ^ ((xbl & 3) << 4));

  float hreg[4] = {0.f, 0.f, 0.f, 0.f};   // fp32 leak state (h0 = 0)

  for (int t = 0; t < T_STEPS; ++t) {
    const u16* Hcur  = Hb + (size_t)(t & 1) * (NROWS * R_DIM);
    u16*       Hnext = Hb + (size_t)((t + 1) & 1) * (NROWS * R_DIM);

    // ---- stage h rows (agent-coherent loads: written by other XCDs) ----
    {
      u64* src = (u64*)(Hcur + row0 * R_DIM);
#pragma unroll
      for (int it = 0; it < 16; ++it) {   // one 2KB row per iteration
        u64 v = __hip_atomic_load(src + it * 256 + tid,
                                  __ATOMIC_RELAXED, __HIP_MEMORY_SCOPE_AGENT);
        *(u64*)(smb + it * 2048 + ((tid * 8) ^ ((it & 7) << 4))) = v;
      }
      // stage x hi/lo slices (read-only data: normal loads)
      const u16* xs = (xhalf ? Xlo : Xhi) + (size_t)t * 8192 + (b0 + xbl) * 256;
      uint4 xv = *(const uint4*)((const char*)xs + xcolb);
      *(uint4*)xdst = xv;
    }
    __syncthreads();

    // ---- z = [h ; xhi+xlo] @ [W ; Wihi+Wilo], two acc chains ---------------
    f32x4 acc0 = {0.f, 0.f, 0.f, 0.f};
    f32x4 acc1 = {0.f, 0.f, 0.f, 0.f};
#pragma unroll
    for (int kt = 0; kt < 32; kt += 2) {
      int colb0 = (kt << 6) + (kb << 4);
      int colb1 = ((kt + 1) << 6) + (kb << 4);
      bf16x8 a0 = *(const bf16x8*)(smb + m * 2048 + (colb0 ^ ((m & 7) << 4)));
      bf16x8 a1 = *(const bf16x8*)(smb + m * 2048 + (colb1 ^ ((m & 7) << 4)));
      acc0 = __builtin_amdgcn_mfma_f32_16x16x32_bf16(a0, bh[kt], acc0, 0, 0, 0);
      acc1 = __builtin_amdgcn_mfma_f32_16x16x32_bf16(a1, bh[kt + 1], acc1, 0, 0, 0);
    }
    {
      const char* xbh = smb + 32768 + (m >> 2) * 512;
      const char* xbl16 = xbh + 2048;
#pragma unroll 2
      for (int kt = 0; kt < 8; ++kt) {    // input part, hi/lo split (3 terms)
        int colb = (kt << 6) + (kb << 4);
        int sco  = colb ^ (((m >> 2) & 3) << 4);
        bf16x8 axh = *(const bf16x8*)(xbh + sco);
        bf16x8 axl = *(const bf16x8*)(xbl16 + sco);
        acc0 = __builtin_amdgcn_mfma_f32_16x16x32_bf16(axh, bh[32 + kt], acc0, 0, 0, 0);
        acc1 = __builtin_amdgcn_mfma_f32_16x16x32_bf16(axh, bl[kt],      acc1, 0, 0, 0);
        acc0 = __builtin_amdgcn_mfma_f32_16x16x32_bf16(axl, bh[32 + kt], acc0, 0, 0, 0);
      }
    }
    f32x4 acc = acc0 + acc1;

    // ---- epilogue: D[row=(kb*4+r)][col=m]; leak in fp32 --------------------
#pragma unroll
    for (int r = 0; r < 4; ++r) {
      int grow = row0 + (kb << 2) + r;
      int gcol = n0 + m;
      float hn = 0.5f * tanhf(acc[r]) + 0.5f * hreg[r];
      hreg[r] = hn;
      Hnext[grow * R_DIM + gcol] = f2bf(hn);
      __builtin_nontemporal_store(hn, &out[((size_t)grow * T_STEPS + t) * R_DIM + gcol]);
    }

    // ---- grid barrier: fence + split arrive + done + release ---------------
    __syncthreads();   // vmcnt(0): all waves' stores in L2
    if (t < T_STEPS - 1) {
      if (tid == 0) {
        __threadfence();  // wbl2: make Hnext visible at coherence point
        u32 prev = __hip_atomic_fetch_add(bar + ((wg & 7) << 6), 1u,
                        __ATOMIC_RELAXED, __HIP_MEMORY_SCOPE_AGENT);
        if (prev == 16u * (u32)(t + 1) - 1u) {          // slot complete (16 WGs)
          u32 d = __hip_atomic_fetch_add(bar + (8 << 6), 1u,
                        __ATOMIC_RELAXED, __HIP_MEMORY_SCOPE_AGENT);
          if (d == 8u * (u32)(t + 1) - 1u) {            // all 8 slots complete
            __hip_atomic_store(bar + (9 << 6), (u32)(t + 1),
                               __ATOMIC_RELAXED, __HIP_MEMORY_SCOPE_AGENT);
          }
        }
        while (__hip_atomic_load(bar + (9 << 6), __ATOMIC_RELAXED,
                                 __HIP_MEMORY_SCOPE_AGENT) < (u32)(t + 1)) {
          __builtin_amdgcn_s_sleep(2);
        }
      }
      __syncthreads();
    }
  }
}

// ============================================================================
extern "C" void kernel_launch(void* const* d_in, const int* in_sizes, int n_in,
                              void* d_out, int out_size, void* d_ws, size_t ws_size,
                              hipStream_t stream) {
  (void)in_sizes; (void)n_in; (void)out_size; (void)ws_size;
  const float* x  = (const float*)d_in[0];   // [32,4,512,64]
  const float* Wi = (const float*)d_in[1];   // [1024,256]
  const float* W  = (const float*)d_in[2];   // [1024,1024]
  float* out = (float*)d_out;                // [32,4,512,1024]

  char* ws  = (char*)d_ws;
  u16*  whi = (u16*)(ws + OFF_WHI);
  u16*  wlo = (u16*)(ws + OFF_WLO);
  u16*  xhi = (u16*)(ws + OFF_XHI);
  u16*  xlo = (u16*)(ws + OFF_XLO);
  u16*  hb  = (u16*)(ws + OFF_HB);
  u32*  bar = (u32*)(ws + OFF_BAR);

  // zero h0 double-buffer + barrier counters (monotonic per launch!)
  hipMemsetAsync(ws + OFF_HB, 0, 2 * 128 * 1024 * 2 + 4096, stream);

  hipLaunchKernelGGL(prep_w, dim3(5, 1024), dim3(256), 0, stream, W, Wi, whi, wlo);
  hipLaunchKernelGGL(prep_x, dim3(512, 32), dim3(256), 0, stream, x, xhi, xlo);
  hipLaunchKernelGGL(esn_scan, dim3(NWG), dim3(TPB), 0, stream,
                     whi, wlo, xhi, xlo, hb, out, bar);
}

// Round 6
// 3204.716 us; speedup vs baseline: 2.8707x; 2.0625x over previous
//
#include <hip/hip_runtime.h>
#include <hip/hip_bf16.h>
#include <cstdint>
#include <cstddef>

// ============================================================================
// EchoStateNetwork: h_{t+1} = 0.5*tanh(h_t @ W + U[t]) + 0.5*h_t
// U = x_t @ Wi^T precomputed (fp32). Persistent 256-WG scan:
//   WG (j,q): col-tile j (16 cols) x row-quarter q (32 rows).
//   4 waves split K=1024 (8 k-tiles each); W register-resident (32 VGPR/wave).
//   Cross-wave reduction via LDS. One __threadfence per XCD per step
//   (census + elected flusher); per-WG L1 buffer_inv; plain A-loads (L2 dedup).
//
// ws layout:
//   Whi [1024 n][1024 k] bf16                                   2 MB
//   U   [512 t][32 b][1024 n] f32                              64 MB
//   Hb2 [2][64 j][128 row][16 col] bf16 (line-exclusive)      512 KB
//   bar census[8]/cb/arrive[8]/done/release (256B apart)        8 KB
// ============================================================================

typedef unsigned short u16;
typedef unsigned int   u32;
typedef unsigned long long u64;
typedef __bf16 bf16x8 __attribute__((ext_vector_type(8)));
typedef float  f32x4  __attribute__((ext_vector_type(4)));
typedef float  f32x2  __attribute__((ext_vector_type(2)));

#define T_STEPS 512
#define NWG     256
#define TPB     256

#define OFF_WHI 0
#define OFF_U   (2*1024*1024)
#define OFF_HB  (OFF_U + (size_t)512*32*1024*4)
#define HB_BYTES ((size_t)64*128*32)            // 256 KB per buffer
#define OFF_BAR (OFF_HB + 2*HB_BYTES)

__device__ __forceinline__ u16 f2bf(float f) {
  u32 u = __builtin_bit_cast(u32, f);
  u += 0x7fffu + ((u >> 16) & 1u);
  return (u16)(u >> 16);
}
__device__ __forceinline__ void pinv(bf16x8& v) { asm volatile("" : "+v"(v)); }

__device__ __forceinline__ u32 AADD(u32* p, u32 v) {
  return __hip_atomic_fetch_add(p, v, __ATOMIC_RELAXED, __HIP_MEMORY_SCOPE_AGENT);
}
__device__ __forceinline__ u32 ALD(u32* p) {
  return __hip_atomic_load(p, __ATOMIC_RELAXED, __HIP_MEMORY_SCOPE_AGENT);
}
__device__ __forceinline__ void AST(u32* p, u32 v) {
  __hip_atomic_store(p, v, __ATOMIC_RELAXED, __HIP_MEMORY_SCOPE_AGENT);
}

// --- prep: Whi[n][k] = bf16(W[k][n]) ----------------------------------------
__global__ void prep_w(const float* __restrict__ W, u16* __restrict__ whi) {
  int n = blockIdx.y;
  int k = blockIdx.x * 256 + threadIdx.x;
  whi[n * 1024 + k] = f2bf(W[k * 1024 + n]);
}

// --- prep: U[t][b][n] = sum_j xt[b][t][j] * Wi[n][j]  (fp32) ---------------
__global__ void prep_u(const float* __restrict__ x, const float* __restrict__ Wi,
                       float* __restrict__ U) {
  __shared__ float wi_t[256][64];   // [j][n']  64 KB
  __shared__ float xt[32][256];     // 32 KB
  const int b = blockIdx.x, nt = blockIdx.y, tid = threadIdx.x;
  // stage Wi rows nt*64..+64 transposed
  {
    int n = tid >> 2, jc = (tid & 3) * 64;
    const float* src = Wi + (size_t)(nt * 64 + n) * 256 + jc;
#pragma unroll
    for (int i = 0; i < 64; i += 4) {
      float4 v = *(const float4*)(src + i);
      wi_t[jc + i + 0][n] = v.x; wi_t[jc + i + 1][n] = v.y;
      wi_t[jc + i + 2][n] = v.z; wi_t[jc + i + 3][n] = v.w;
    }
  }
  const int wv = tid >> 6, nn = tid & 63;
  for (int tc = 0; tc < 16; ++tc) {
    __syncthreads();
    // stage xt[32][256] for t = tc*32 + tt
    for (int s = 0; s < 8; ++s) {
      int fi = s * 256 + tid;
      int tt = fi >> 6, j4 = (fi & 63) * 4;
      int c = j4 >> 6, i = j4 & 63;
      float4 v = *(const float4*)(x + ((size_t)((b * 4 + c) * 512) + tc * 32 + tt) * 64 + i);
      *(float4*)&xt[tt][j4] = v;
    }
    __syncthreads();
    float acc[8] = {0,0,0,0,0,0,0,0};
    for (int j4 = 0; j4 < 64; ++j4) {
      float w0 = wi_t[j4 * 4 + 0][nn], w1 = wi_t[j4 * 4 + 1][nn];
      float w2 = wi_t[j4 * 4 + 2][nn], w3 = wi_t[j4 * 4 + 3][nn];
#pragma unroll
      for (int tt = 0; tt < 8; ++tt) {
        float4 xv = *(const float4*)&xt[wv * 8 + tt][j4 * 4];
        acc[tt] += xv.x * w0 + xv.y * w1 + xv.z * w2 + xv.w * w3;
      }
    }
#pragma unroll
    for (int tt = 0; tt < 8; ++tt)
      U[((size_t)(tc * 32 + wv * 8 + tt) * 32 + b) * 1024 + nt * 64 + nn] = acc[tt];
  }
}

// --- the scan ---------------------------------------------------------------
__global__ void __launch_bounds__(TPB, 1) esn_scan(
    const u16* __restrict__ Whi, const float* __restrict__ U,
    u16* __restrict__ Hb, float* __restrict__ out, u32* __restrict__ bar) {
  __shared__ __align__(16) float red[4 * 2 * 64 * 4];   // [w][m][lane][r] 8 KB

  const int wg = blockIdx.x, tid = threadIdx.x;
  const int j = wg >> 2, q = wg & 3;        // col-tile, row-quarter
  const int wv = tid >> 6, lane = tid & 63;
  const int mcol = lane & 15, kb = lane >> 4;
  const int c0 = j << 4, r0 = q << 5;

  // ---- W fragments: kt = wv + idx*4, idx 0..7 (32 VGPRs, pinned) ----------
  bf16x8 bh[8];
  {
    const char* wb = (const char*)Whi + (size_t)(c0 + mcol) * 2048 + kb * 16;
#pragma unroll
    for (int idx = 0; idx < 8; ++idx)
      bh[idx] = *(const bf16x8*)(wb + (size_t)(wv + idx * 4) * 64);
#pragma unroll
    for (int idx = 0; idx < 8; ++idx) pinv(bh[idx]);
  }

  // ---- census: discover XCD placement (one-time) --------------------------
  int xcd = 0; u32 my_n = 0, nx = 0;
  if (tid == 0) {
    asm volatile("s_getreg_b32 %0, hwreg(HW_REG_XCC_ID)" : "=s"(xcd));
    xcd &= 7;
    AADD(bar + xcd * 64, 1u);
    AADD(bar + 8 * 64, 1u);
    while (ALD(bar + 8 * 64) < (u32)NWG) __builtin_amdgcn_s_sleep(2);
    my_n = ALD(bar + xcd * 64);
    for (int k = 0; k < 8; ++k) nx += (ALD(bar + k * 64) > 0u) ? 1u : 0u;
  }
  __syncthreads();

  float hreg[2] = {0.f, 0.f};

  for (int t = 0; t < T_STEPS; ++t) {
    const char* Hc = (const char*)Hb + (size_t)(t & 1) * HB_BYTES;

    // ---- z = h @ W : pipelined A-loads (plain, L2-dedup) + MFMA -----------
    f32x4 acc0 = {0.f, 0.f, 0.f, 0.f};
    f32x4 acc1 = {0.f, 0.f, 0.f, 0.f};
    uint4 ab[2][2];
#define LOADA(slot, idx_) { \
      int kt_ = wv + (idx_) * 4; \
      size_t base_ = (size_t)(kt_ * 2 + (kb >> 1)) * 4096 + (size_t)(kb & 1) * 16; \
      ab[slot][0] = *(const uint4*)(Hc + base_ + (size_t)(r0 + mcol) * 32); \
      ab[slot][1] = *(const uint4*)(Hc + base_ + (size_t)(r0 + 16 + mcol) * 32); }
    LOADA(0, 0)
    LOADA(1, 1)
#pragma unroll
    for (int idx = 0; idx < 8; ++idx) {
      bf16x8 a0 = __builtin_bit_cast(bf16x8, ab[idx & 1][0]);
      bf16x8 a1 = __builtin_bit_cast(bf16x8, ab[idx & 1][1]);
      acc0 = __builtin_amdgcn_mfma_f32_16x16x32_bf16(a0, bh[idx], acc0, 0, 0, 0);
      acc1 = __builtin_amdgcn_mfma_f32_16x16x32_bf16(a1, bh[idx], acc1, 0, 0, 0);
      if (idx < 6) LOADA(idx & 1, idx + 2)
    }
#undef LOADA

    // ---- cross-wave K reduction via LDS -----------------------------------
    *(f32x4*)&red[((wv * 2 + 0) * 64 + lane) * 4] = acc0;
    *(f32x4*)&red[((wv * 2 + 1) * 64 + lane) * 4] = acc1;
    __syncthreads();

    // ---- epilogue: 2 outputs per thread -----------------------------------
    {
      int row_l = tid >> 3;                 // 0..31
      int col0  = (tid & 7) * 2;            // 0..14
      int m = row_l >> 4, rr = row_l & 15;
      int kbq = rr >> 2, r = rr & 3;
      int grow = r0 + row_l;
      const float* up = U + ((size_t)t * 32 + (grow >> 2)) * 1024 + c0 + col0;
      float z0 = 0.f, z1 = 0.f;
#pragma unroll
      for (int w = 0; w < 4; ++w) {
        z0 += red[((w * 2 + m) * 64 + kbq * 16 + col0 + 0) * 4 + r];
        z1 += red[((w * 2 + m) * 64 + kbq * 16 + col0 + 1) * 4 + r];
      }
      float hn0 = 0.5f * tanhf(z0 + up[0]) + 0.5f * hreg[0];
      float hn1 = 0.5f * tanhf(z1 + up[1]) + 0.5f * hreg[1];
      hreg[0] = hn0; hreg[1] = hn1;
      u16* Hn = (u16*)((char*)Hb + (size_t)((t + 1) & 1) * HB_BYTES);
      u32 pk = (u32)f2bf(hn0) | ((u32)f2bf(hn1) << 16);
      *(u32*)(Hn + ((size_t)j * 128 + grow) * 16 + col0) = pk;
      f32x2 o2; o2.x = hn0; o2.y = hn1;
      __builtin_nontemporal_store(o2,
          (f32x2*)(out + ((size_t)grow * 512 + t) * 1024 + c0 + col0));
    }
    __syncthreads();   // red reusable; all global stores drained to L2

    // ---- barrier: per-XCD elected flusher + global release ----------------
    if (t < T_STEPS - 1) {
      if (tid == 0) {
        u32 prev = AADD(bar + (16 + xcd) * 64, 1u);
        if (prev == my_n * (u32)(t + 1) - 1u) {     // last arriver on this XCD
          __threadfence();                          // wbl2+inv: L2 -> L3
          u32 d = AADD(bar + 24 * 64, 1u);
          if (d == nx * (u32)(t + 1) - 1u)
            AST(bar + 25 * 64, (u32)(t + 1));
        }
        while (ALD(bar + 25 * 64) < (u32)(t + 1)) __builtin_amdgcn_s_sleep(2);
      }
      __syncthreads();
      // L1 invalidate (per-CU) so plain loads can't hit stale lines
      asm volatile("buffer_inv\n\ts_waitcnt vmcnt(0)" ::: "memory");
    }
  }
}

// ============================================================================
extern "C" void kernel_launch(void* const* d_in, const int* in_sizes, int n_in,
                              void* d_out, int out_size, void* d_ws, size_t ws_size,
                              hipStream_t stream) {
  (void)in_sizes; (void)n_in; (void)out_size; (void)ws_size;
  const float* x  = (const float*)d_in[0];   // [32,4,512,64]
  const float* Wi = (const float*)d_in[1];   // [1024,256]
  const float* W  = (const float*)d_in[2];   // [1024,1024]
  float* out = (float*)d_out;                // [32,4,512,1024]

  char* ws  = (char*)d_ws;
  u16*  whi = (u16*)(ws + OFF_WHI);
  float* U  = (float*)(ws + OFF_U);
  u16*  hb  = (u16*)(ws + OFF_HB);
  u32*  bar = (u32*)(ws + OFF_BAR);

  // zero h0 double-buffer + all barrier/census counters
  (void)hipMemsetAsync(ws + OFF_HB, 0, 2 * HB_BYTES + 8192, stream);

  hipLaunchKernelGGL(prep_w, dim3(4, 1024), dim3(256), 0, stream, W, whi);
  hipLaunchKernelGGL(prep_u, dim3(32, 16), dim3(256), 0, stream, x, Wi, U);
  hipLaunchKernelGGL(esn_scan, dim3(NWG), dim3(TPB), 0, stream,
                     whi, U, hb, out, bar);
}

// Round 7
// 3011.755 us; speedup vs baseline: 3.0546x; 1.0641x over previous
//
#include <hip/hip_runtime.h>
#include <hip/hip_bf16.h>
#include <cstdint>
#include <cstddef>

// ============================================================================
// EchoStateNetwork: h_{t+1} = 0.5*tanh(h_t @ W + U[t]) + 0.5*h_t
// U = x_t @ Wi^T precomputed (fp32). Persistent 256-WG scan:
//   WG (j,q): col-tile j (16 cols) x row-quarter q (32 rows).
//   4 waves split K=1024; W register-resident (32 VGPR/wave, pinned).
//   R7 protocol: Hnext via agent atomic-swap (executes at L3, NO wbl2 fence
//   anywhere); per-WG buffer_inv drops stale clean lines each step; plain
//   A-loads (L2 dedup). Hierarchical arrive(XCD)/done/release barrier.
//
// ws layout:
//   Whi [1024 n][1024 k] bf16                                   2 MB
//   U   [512 t][32 b][1024 n] f32                              64 MB
//   Hb2 [2][64 j][128 row][16 col] bf16 (line-exclusive)      512 KB
//   bar census[8]/cb/arrive[8]/done/release (256B apart)        8 KB
// ============================================================================

typedef unsigned short u16;
typedef unsigned int   u32;
typedef unsigned long long u64;
typedef __bf16 bf16x8 __attribute__((ext_vector_type(8)));
typedef float  f32x4  __attribute__((ext_vector_type(4)));
typedef float  f32x2  __attribute__((ext_vector_type(2)));

#define T_STEPS 512
#define NWG     256
#define TPB     256

#define OFF_WHI 0
#define OFF_U   (2*1024*1024)
#define OFF_HB  (OFF_U + (size_t)512*32*1024*4)
#define HB_BYTES ((size_t)64*128*32)            // 256 KB per buffer
#define OFF_BAR (OFF_HB + 2*HB_BYTES)

__device__ __forceinline__ u16 f2bf(float f) {
  u32 u = __builtin_bit_cast(u32, f);
  u += 0x7fffu + ((u >> 16) & 1u);
  return (u16)(u >> 16);
}
__device__ __forceinline__ void pinv(bf16x8& v) { asm volatile("" : "+v"(v)); }

__device__ __forceinline__ u32 AADD(u32* p, u32 v) {
  return __hip_atomic_fetch_add(p, v, __ATOMIC_RELAXED, __HIP_MEMORY_SCOPE_AGENT);
}
__device__ __forceinline__ u32 ALD(u32* p) {
  return __hip_atomic_load(p, __ATOMIC_RELAXED, __HIP_MEMORY_SCOPE_AGENT);
}
__device__ __forceinline__ void AST(u32* p, u32 v) {
  __hip_atomic_store(p, v, __ATOMIC_RELAXED, __HIP_MEMORY_SCOPE_AGENT);
}

// --- prep: Whi[n][k] = bf16(W[k][n]) ----------------------------------------
__global__ void prep_w(const float* __restrict__ W, u16* __restrict__ whi) {
  int n = blockIdx.y;
  int k = blockIdx.x * 256 + threadIdx.x;
  whi[n * 1024 + k] = f2bf(W[k * 1024 + n]);
}

// --- prep: U[t][b][n] = sum_j xt[b][t][j] * Wi[n][j]  (fp32) ---------------
__global__ void prep_u(const float* __restrict__ x, const float* __restrict__ Wi,
                       float* __restrict__ U) {
  __shared__ float wi_t[256][64];   // [j][n']  64 KB
  __shared__ float xt[32][256];     // 32 KB
  const int b = blockIdx.x, nt = blockIdx.y, tid = threadIdx.x;
  // stage Wi rows nt*64..+64 transposed
  {
    int n = tid >> 2, jc = (tid & 3) * 64;
    const float* src = Wi + (size_t)(nt * 64 + n) * 256 + jc;
#pragma unroll
    for (int i = 0; i < 64; i += 4) {
      float4 v = *(const float4*)(src + i);
      wi_t[jc + i + 0][n] = v.x; wi_t[jc + i + 1][n] = v.y;
      wi_t[jc + i + 2][n] = v.z; wi_t[jc + i + 3][n] = v.w;
    }
  }
  const int wv = tid >> 6, nn = tid & 63;
  for (int tc = 0; tc < 16; ++tc) {
    __syncthreads();
    // stage xt[32][256] for t = tc*32 + tt
    for (int s = 0; s < 8; ++s) {
      int fi = s * 256 + tid;
      int tt = fi >> 6, j4 = (fi & 63) * 4;
      int c = j4 >> 6, i = j4 & 63;
      float4 v = *(const float4*)(x + ((size_t)((b * 4 + c) * 512) + tc * 32 + tt) * 64 + i);
      *(float4*)&xt[tt][j4] = v;
    }
    __syncthreads();
    float acc[8] = {0,0,0,0,0,0,0,0};
    for (int j4 = 0; j4 < 64; ++j4) {
      float w0 = wi_t[j4 * 4 + 0][nn], w1 = wi_t[j4 * 4 + 1][nn];
      float w2 = wi_t[j4 * 4 + 2][nn], w3 = wi_t[j4 * 4 + 3][nn];
#pragma unroll
      for (int tt = 0; tt < 8; ++tt) {
        float4 xv = *(const float4*)&xt[wv * 8 + tt][j4 * 4];
        acc[tt] += xv.x * w0 + xv.y * w1 + xv.z * w2 + xv.w * w3;
      }
    }
#pragma unroll
    for (int tt = 0; tt < 8; ++tt)
      U[((size_t)(tc * 32 + wv * 8 + tt) * 32 + b) * 1024 + nt * 64 + nn] = acc[tt];
  }
}

// --- the scan ---------------------------------------------------------------
__global__ void __launch_bounds__(TPB, 1) esn_scan(
    const u16* __restrict__ Whi, const float* __restrict__ U,
    u16* __restrict__ Hb, float* __restrict__ out, u32* __restrict__ bar) {
  __shared__ __align__(16) float red[4 * 2 * 64 * 4];   // [w][m][lane][r] 8 KB

  const int wg = blockIdx.x, tid = threadIdx.x;
  const int j = wg >> 2, q = wg & 3;        // col-tile, row-quarter
  const int wv = tid >> 6, lane = tid & 63;
  const int mcol = lane & 15, kb = lane >> 4;
  const int c0 = j << 4, r0 = q << 5;

  // ---- W fragments: kt = wv + idx*4, idx 0..7 (32 VGPRs, pinned) ----------
  bf16x8 bh[8];
  {
    const char* wb = (const char*)Whi + (size_t)(c0 + mcol) * 2048 + kb * 16;
#pragma unroll
    for (int idx = 0; idx < 8; ++idx)
      bh[idx] = *(const bf16x8*)(wb + (size_t)(wv + idx * 4) * 64);
#pragma unroll
    for (int idx = 0; idx < 8; ++idx) pinv(bh[idx]);
  }

  // ---- census: discover XCD placement (one-time) --------------------------
  int xcd = 0; u32 my_n = 0, nx = 0;
  if (tid == 0) {
    asm volatile("s_getreg_b32 %0, hwreg(HW_REG_XCC_ID)" : "=s"(xcd));
    xcd &= 7;
    AADD(bar + xcd * 64, 1u);
    AADD(bar + 8 * 64, 1u);
    while (ALD(bar + 8 * 64) < (u32)NWG) __builtin_amdgcn_s_sleep(2);
    my_n = ALD(bar + xcd * 64);
    for (int k = 0; k < 8; ++k) nx += (ALD(bar + k * 64) > 0u) ? 1u : 0u;
  }
  __syncthreads();

  float hreg[2] = {0.f, 0.f};

  for (int t = 0; t < T_STEPS; ++t) {
    const char* Hc = (const char*)Hb + (size_t)(t & 1) * HB_BYTES;

    // ---- z = h @ W : pipelined A-loads (plain, L2-dedup) + MFMA -----------
    f32x4 acc0 = {0.f, 0.f, 0.f, 0.f};
    f32x4 acc1 = {0.f, 0.f, 0.f, 0.f};
    uint4 ab[2][2];
#define LOADA(slot, idx_) { \
      int kt_ = wv + (idx_) * 4; \
      size_t base_ = (size_t)(kt_ * 2 + (kb >> 1)) * 4096 + (size_t)(kb & 1) * 16; \
      ab[slot][0] = *(const uint4*)(Hc + base_ + (size_t)(r0 + mcol) * 32); \
      ab[slot][1] = *(const uint4*)(Hc + base_ + (size_t)(r0 + 16 + mcol) * 32); }
    LOADA(0, 0)
    LOADA(1, 1)
#pragma unroll
    for (int idx = 0; idx < 8; ++idx) {
      bf16x8 a0 = __builtin_bit_cast(bf16x8, ab[idx & 1][0]);
      bf16x8 a1 = __builtin_bit_cast(bf16x8, ab[idx & 1][1]);
      acc0 = __builtin_amdgcn_mfma_f32_16x16x32_bf16(a0, bh[idx], acc0, 0, 0, 0);
      acc1 = __builtin_amdgcn_mfma_f32_16x16x32_bf16(a1, bh[idx], acc1, 0, 0, 0);
      if (idx < 6) LOADA(idx & 1, idx + 2)
    }
#undef LOADA

    // ---- cross-wave K reduction via LDS -----------------------------------
    *(f32x4*)&red[((wv * 2 + 0) * 64 + lane) * 4] = acc0;
    *(f32x4*)&red[((wv * 2 + 1) * 64 + lane) * 4] = acc1;
    __syncthreads();

    // ---- epilogue: 2 outputs per thread -----------------------------------
    {
      int row_l = tid >> 3;                 // 0..31
      int col0  = (tid & 7) * 2;            // 0..14
      int m = row_l >> 4, rr = row_l & 15;
      int kbq = rr >> 2, r = rr & 3;
      int grow = r0 + row_l;
      const float* up = U + ((size_t)t * 32 + (grow >> 2)) * 1024 + c0 + col0;
      float z0 = 0.f, z1 = 0.f;
#pragma unroll
      for (int w = 0; w < 4; ++w) {
        z0 += red[((w * 2 + m) * 64 + kbq * 16 + col0 + 0) * 4 + r];
        z1 += red[((w * 2 + m) * 64 + kbq * 16 + col0 + 1) * 4 + r];
      }
      float hn0 = 0.5f * tanhf(z0 + up[0]) + 0.5f * hreg[0];
      float hn1 = 0.5f * tanhf(z1 + up[1]) + 0.5f * hreg[1];
      hreg[0] = hn0; hreg[1] = hn1;
      u16* Hn = (u16*)((char*)Hb + (size_t)((t + 1) & 1) * HB_BYTES);
      u32 pk = (u32)f2bf(hn0) | ((u32)f2bf(hn1) << 16);
      // agent-scope swap: executes at the L3 coherence point (no fence needed)
      u32* hdst = (u32*)(Hn + ((size_t)j * 128 + grow) * 16 + col0);
      (void)__hip_atomic_exchange(hdst, pk, __ATOMIC_RELAXED,
                                  __HIP_MEMORY_SCOPE_AGENT);
      f32x2 o2; o2.x = hn0; o2.y = hn1;
      __builtin_nontemporal_store(o2,
          (f32x2*)(out + ((size_t)grow * 512 + t) * 1024 + c0 + col0));
    }
    __syncthreads();   // red reusable; vmcnt(0): all waves' swaps acked at L3

    // ---- barrier: hierarchical arrive(XCD) -> done -> release (all L3) ----
    if (t < T_STEPS - 1) {
      if (tid == 0) {
        u32 prev = AADD(bar + (16 + xcd) * 64, 1u);
        if (prev == my_n * (u32)(t + 1) - 1u) {     // last arriver on this XCD
          u32 d = AADD(bar + 24 * 64, 1u);
          if (d == nx * (u32)(t + 1) - 1u)
            AST(bar + 25 * 64, (u32)(t + 1));
        }
        while (ALD(bar + 25 * 64) < (u32)(t + 1)) __builtin_amdgcn_s_sleep(2);
      }
      __syncthreads();
      // invalidate clean L1/L2 lines so next-step loads can't hit stale h
      asm volatile("buffer_inv\n\ts_waitcnt vmcnt(0)" ::: "memory");
    }
  }
}

// ============================================================================
extern "C" void kernel_launch(void* const* d_in, const int* in_sizes, int n_in,
                              void* d_out, int out_size, void* d_ws, size_t ws_size,
                              hipStream_t stream) {
  (void)in_sizes; (void)n_in; (void)out_size; (void)ws_size;
  const float* x  = (const float*)d_in[0];   // [32,4,512,64]
  const float* Wi = (const float*)d_in[1];   // [1024,256]
  const float* W  = (const float*)d_in[2];   // [1024,1024]
  float* out = (float*)d_out;                // [32,4,512,1024]

  char* ws  = (char*)d_ws;
  u16*  whi = (u16*)(ws + OFF_WHI);
  float* U  = (float*)(ws + OFF_U);
  u16*  hb  = (u16*)(ws + OFF_HB);
  u32*  bar = (u32*)(ws + OFF_BAR);

  // zero h0 double-buffer + all barrier/census counters
  (void)hipMemsetAsync(ws + OFF_HB, 0, 2 * HB_BYTES + 8192, stream);

  hipLaunchKernelGGL(prep_w, dim3(4, 1024), dim3(256), 0, stream, W, whi);
  hipLaunchKernelGGL(prep_u, dim3(32, 16), dim3(256), 0, stream, x, Wi, U);
  hipLaunchKernelGGL(esn_scan, dim3(NWG), dim3(TPB), 0, stream,
                     whi, U, hb, out, bar);
}

// Round 8
// 2244.630 us; speedup vs baseline: 4.0986x; 1.3418x over previous
//
#include <hip/hip_runtime.h>
#include <hip/hip_bf16.h>
#include <cstdint>
#include <cstddef>

// ============================================================================
// EchoStateNetwork: h_{t+1} = 0.5*tanh(h_t @ W + U[t]) + 0.5*h_t
// U precomputed fp32. Persistent 256-WG scan, 8 independent row-groups:
//   WG (q,j): rows q*16..+16, cols j*32..+32. 4 waves split K=1024.
//   W register-resident (64 VGPR/wave, pinned). h read via agent atomic loads
//   straight into A-frags (no LDS staging, no buffer_inv); h written via u32
//   agent swaps (R7-proven). Per-row-group 32-WG flag-line barrier:
//   store flag -> poll one 128B line. out[] = full-line nt-stores (no RFO),
//   issued after flag store to overlap poll.
//
// ws layout:
//   Whi [1024 n][1024 k] bf16                                   2 MB
//   U   [512 t][32 b][1024 n] f32                              64 MB
//   Hb2 [2][128 row][1024 col] bf16                           512 KB
//   bar flags[8 groups][32 slots] u32 (one 128B line/group)     8 KB
// ============================================================================

typedef unsigned short u16;
typedef unsigned int   u32;
typedef unsigned long long u64;
typedef __bf16 bf16x8 __attribute__((ext_vector_type(8)));
typedef u64    u64x2  __attribute__((ext_vector_type(2)));
typedef float  f32x4  __attribute__((ext_vector_type(4)));
typedef float  f32x2  __attribute__((ext_vector_type(2)));

#define T_STEPS 512
#define NWG     256
#define TPB     256

#define OFF_WHI 0
#define OFF_U   (2*1024*1024)
#define OFF_HB  (OFF_U + (size_t)512*32*1024*4)
#define HB_BYTES ((size_t)128*2048)             // 256 KB per buffer
#define OFF_BAR (OFF_HB + 2*HB_BYTES)

__device__ __forceinline__ u16 f2bf(float f) {
  u32 u = __builtin_bit_cast(u32, f);
  u += 0x7fffu + ((u >> 16) & 1u);
  return (u16)(u >> 16);
}
__device__ __forceinline__ void pinv(bf16x8& v) { asm volatile("" : "+v"(v)); }

__device__ __forceinline__ u32 ALD(const u32* p) {
  return __hip_atomic_load(p, __ATOMIC_RELAXED, __HIP_MEMORY_SCOPE_AGENT);
}
__device__ __forceinline__ u64 ALD64(const u64* p) {
  return __hip_atomic_load(p, __ATOMIC_RELAXED, __HIP_MEMORY_SCOPE_AGENT);
}
__device__ __forceinline__ void AST(u32* p, u32 v) {
  __hip_atomic_store(p, v, __ATOMIC_RELAXED, __HIP_MEMORY_SCOPE_AGENT);
}

// --- prep: Whi[n][k] = bf16(W[k][n]) ----------------------------------------
__global__ void prep_w(const float* __restrict__ W, u16* __restrict__ whi) {
  int n = blockIdx.y;
  int k = blockIdx.x * 256 + threadIdx.x;
  whi[n * 1024 + k] = f2bf(W[k * 1024 + n]);
}

// --- prep: U[t][b][n] = sum_j xt[b][t][j] * Wi[n][j]  (fp32) ---------------
__global__ void prep_u(const float* __restrict__ x, const float* __restrict__ Wi,
                       float* __restrict__ U) {
  __shared__ float wi_t[256][64];
  __shared__ float xt[32][256];
  const int b = blockIdx.x, nt = blockIdx.y, tid = threadIdx.x;
  {
    int n = tid >> 2, jc = (tid & 3) * 64;
    const float* src = Wi + (size_t)(nt * 64 + n) * 256 + jc;
#pragma unroll
    for (int i = 0; i < 64; i += 4) {
      float4 v = *(const float4*)(src + i);
      wi_t[jc + i + 0][n] = v.x; wi_t[jc + i + 1][n] = v.y;
      wi_t[jc + i + 2][n] = v.z; wi_t[jc + i + 3][n] = v.w;
    }
  }
  const int wv = tid >> 6, nn = tid & 63;
  for (int tc = 0; tc < 16; ++tc) {
    __syncthreads();
    for (int s = 0; s < 8; ++s) {
      int fi = s * 256 + tid;
      int tt = fi >> 6, j4 = (fi & 63) * 4;
      int c = j4 >> 6, i = j4 & 63;
      float4 v = *(const float4*)(x + ((size_t)((b * 4 + c) * 512) + tc * 32 + tt) * 64 + i);
      *(float4*)&xt[tt][j4] = v;
    }
    __syncthreads();
    float acc[8] = {0,0,0,0,0,0,0,0};
    for (int j4 = 0; j4 < 64; ++j4) {
      float w0 = wi_t[j4 * 4 + 0][nn], w1 = wi_t[j4 * 4 + 1][nn];
      float w2 = wi_t[j4 * 4 + 2][nn], w3 = wi_t[j4 * 4 + 3][nn];
#pragma unroll
      for (int tt = 0; tt < 8; ++tt) {
        float4 xv = *(const float4*)&xt[wv * 8 + tt][j4 * 4];
        acc[tt] += xv.x * w0 + xv.y * w1 + xv.z * w2 + xv.w * w3;
      }
    }
#pragma unroll
    for (int tt = 0; tt < 8; ++tt)
      U[((size_t)(tc * 32 + wv * 8 + tt) * 32 + b) * 1024 + nt * 64 + nn] = acc[tt];
  }
}

// --- the scan ---------------------------------------------------------------
__global__ void __launch_bounds__(TPB, 1) esn_scan(
    const u16* __restrict__ Whi, const float* __restrict__ U,
    u16* __restrict__ Hb, float* __restrict__ out, u32* __restrict__ bar) {
  __shared__ __align__(16) float red[8 * 64 * 4];   // [wv*2+nt][lane][r] 8 KB

  const int wg = blockIdx.x, tid = threadIdx.x;
  const int q = wg & 7, j = wg >> 3;        // row-group (16 rows), col-tile (32)
  const int wv = tid >> 6, lane = tid & 63;
  const int mcol = lane & 15, kb = lane >> 4;
  const int r0 = q << 4, c0 = j << 5;

  // ---- W fragments: [ntile 2][kt 8] = 64 VGPRs, pinned --------------------
  bf16x8 bh[2][8];
#pragma unroll
  for (int nt = 0; nt < 2; ++nt) {
    const char* wb = (const char*)Whi + (size_t)(c0 + nt * 16 + mcol) * 2048
                     + wv * 512 + kb * 16;
#pragma unroll
    for (int kt = 0; kt < 8; ++kt)
      bh[nt][kt] = *(const bf16x8*)(wb + kt * 64);
  }
#pragma unroll
  for (int nt = 0; nt < 2; ++nt)
#pragma unroll
    for (int kt = 0; kt < 8; ++kt) pinv(bh[nt][kt]);

  // ---- per-thread output mapping ------------------------------------------
  const int row_l = tid >> 4;               // 0..15
  const int col0  = (tid & 15) * 2;         // 0..30
  const int grow  = r0 + row_l;
  const int ont   = col0 >> 4, oci = col0 & 15;
  const int okb   = row_l >> 2, orr = row_l & 3;
  u32* flags = bar + q * 32;                // one 128B line per group

  float hreg[2] = {0.f, 0.f};
  // U[0] prefetch
  f32x2 uf = *(const f32x2*)(U + (size_t)(grow >> 2) * 1024 + c0 + col0);

  for (int t = 0; t < T_STEPS; ++t) {
    // ---- A-fragments: agent atomic loads straight from L3 -----------------
    const char* hsrc = (const char*)Hb + (size_t)(t & 1) * HB_BYTES
                       + (size_t)(r0 + mcol) * 2048 + wv * 512 + kb * 16;
    u64 ab[8][2];
#pragma unroll
    for (int kt = 0; kt < 8; ++kt) {
      ab[kt][0] = ALD64((const u64*)(hsrc + kt * 64));
      ab[kt][1] = ALD64((const u64*)(hsrc + kt * 64 + 8));
    }

    // ---- z = h @ W (2 acc chains over ntiles, shared A) --------------------
    f32x4 acc0 = {0.f, 0.f, 0.f, 0.f};
    f32x4 acc1 = {0.f, 0.f, 0.f, 0.f};
#pragma unroll
    for (int kt = 0; kt < 8; ++kt) {
      u64x2 av; av.x = ab[kt][0]; av.y = ab[kt][1];
      bf16x8 a = __builtin_bit_cast(bf16x8, av);
      acc0 = __builtin_amdgcn_mfma_f32_16x16x32_bf16(a, bh[0][kt], acc0, 0, 0, 0);
      acc1 = __builtin_amdgcn_mfma_f32_16x16x32_bf16(a, bh[1][kt], acc1, 0, 0, 0);
    }

    // ---- cross-wave K reduction via LDS -----------------------------------
    *(f32x4*)&red[((wv * 2 + 0) * 64 + lane) * 4] = acc0;
    *(f32x4*)&red[((wv * 2 + 1) * 64 + lane) * 4] = acc1;
    __syncthreads();

    // ---- epilogue ----------------------------------------------------------
    float z0 = 0.f, z1 = 0.f;
#pragma unroll
    for (int w = 0; w < 4; ++w) {
      z0 += red[((w * 2 + ont) * 64 + okb * 16 + oci + 0) * 4 + orr];
      z1 += red[((w * 2 + ont) * 64 + okb * 16 + oci + 1) * 4 + orr];
    }
    float hn0 = 0.5f * tanhf(z0 + uf.x) + 0.5f * hreg[0];
    float hn1 = 0.5f * tanhf(z1 + uf.y) + 0.5f * hreg[1];
    hreg[0] = hn0; hreg[1] = hn1;

    // h swap-store (executes at L3) then drain
    {
      u32 pk = (u32)f2bf(hn0) | ((u32)f2bf(hn1) << 16);
      u32* hdst = (u32*)((char*)Hb + (size_t)((t + 1) & 1) * HB_BYTES
                         + (size_t)grow * 2048 + (c0 + col0) * 2);
      (void)__hip_atomic_exchange(hdst, pk, __ATOMIC_RELAXED,
                                  __HIP_MEMORY_SCOPE_AGENT);
    }
    asm volatile("s_waitcnt vmcnt(0)" ::: "memory");   // swap acked at L3
    __syncthreads();                                    // all threads acked

    if (t < T_STEPS - 1) {
      if (tid == 0) AST(flags + j, (u32)(t + 1));       // announce
    }

    // out[] full-line nt-store (overlaps poll) + U[t+1] prefetch
    {
      f32x2 o2; o2.x = hn0; o2.y = hn1;
      __builtin_nontemporal_store(o2,
          (f32x2*)(out + ((size_t)grow * 512 + t) * 1024 + c0 + col0));
    }
    if (t < T_STEPS - 1) {
      uf = *(const f32x2*)(U + ((size_t)(t + 1) * 32 + (grow >> 2)) * 1024 + c0 + col0);
      // ---- poll the group's flag line (wave 0 only) ------------------------
      if (wv == 0) {
        u32 tgt = (u32)(t + 1);
        while (true) {
          u32 v = ALD(flags + (lane & 31));
          if (__all(v >= tgt)) break;
          __builtin_amdgcn_s_sleep(1);
        }
      }
      __syncthreads();
    }
  }
}

// ============================================================================
extern "C" void kernel_launch(void* const* d_in, const int* in_sizes, int n_in,
                              void* d_out, int out_size, void* d_ws, size_t ws_size,
                              hipStream_t stream) {
  (void)in_sizes; (void)n_in; (void)out_size; (void)ws_size;
  const float* x  = (const float*)d_in[0];   // [32,4,512,64]
  const float* Wi = (const float*)d_in[1];   // [1024,256]
  const float* W  = (const float*)d_in[2];   // [1024,1024]
  float* out = (float*)d_out;                // [32,4,512,1024]

  char* ws  = (char*)d_ws;
  u16*  whi = (u16*)(ws + OFF_WHI);
  float* U  = (float*)(ws + OFF_U);
  u16*  hb  = (u16*)(ws + OFF_HB);
  u32*  bar = (u32*)(ws + OFF_BAR);

  // zero h0 double-buffer + flag lines (monotonic per launch)
  (void)hipMemsetAsync(ws + OFF_HB, 0, 2 * HB_BYTES + 8192, stream);

  hipLaunchKernelGGL(prep_w, dim3(4, 1024), dim3(256), 0, stream, W, whi);
  hipLaunchKernelGGL(prep_u, dim3(32, 16), dim3(256), 0, stream, x, Wi, U);
  hipLaunchKernelGGL(esn_scan, dim3(NWG), dim3(TPB), 0, stream,
                     whi, U, hb, out, bar);
}

// Round 9
// 1689.769 us; speedup vs baseline: 5.4444x; 1.3284x over previous
//
#include <hip/hip_runtime.h>
#include <hip/hip_bf16.h>
#include <cstdint>
#include <cstddef>

// ============================================================================
// EchoStateNetwork: h_{t+1} = 0.5*tanh(h_t @ W + U[t]) + 0.5*h_t
// U precomputed fp32. Persistent 256-WG scan, 8 independent row-groups.
// R9: XCD-LOCAL protocol. Census maps row-group g -> XCD g (32 WGs each,
// claimed via per-XCD slot counters). All h exchange + flags stay in the
// XCD's L2: plain stores (ack at L2), buffer_inv(L1)+plain-load polling,
// plain dedup'd h loads. No L3 round trips, no global barrier.
// Fallback (any non-uniform placement): R8 L3 protocol (swap + L3 flags +
// agent atomic loads) — correct for arbitrary placement.
//
// ws layout:
//   Whi [1024 n][1024 k] bf16                                   2 MB
//   U   [512 t][32 b][1024 n] f32                              64 MB
//   Hb2 [2][128 row][1024 col] bf16 (32KB/group, group-local) 512 KB
//   bar census[8]/cb/claim[8] (u32, 256B apart) + flag lines   16 KB
// ============================================================================

typedef unsigned short u16;
typedef unsigned int   u32;
typedef unsigned long long u64;
typedef __bf16 bf16x8 __attribute__((ext_vector_type(8)));
typedef u64    u64x2  __attribute__((ext_vector_type(2)));
typedef float  f32x4  __attribute__((ext_vector_type(4)));
typedef float  f32x2  __attribute__((ext_vector_type(2)));

#define T_STEPS 512
#define NWG     256
#define TPB     256

#define OFF_WHI 0
#define OFF_U   (2*1024*1024)
#define OFF_HB  (OFF_U + (size_t)512*32*1024*4)
#define HB_BYTES ((size_t)128*2048)             // 256 KB per buffer
#define OFF_BAR (OFF_HB + 2*HB_BYTES)
// bar (u32 indices): census[x]=x*64, cb=512, claim[x]=(9+x)*64, flags[g]=2048+g*64

__device__ __forceinline__ u16 f2bf(float f) {
  u32 u = __builtin_bit_cast(u32, f);
  u += 0x7fffu + ((u >> 16) & 1u);
  return (u16)(u >> 16);
}
__device__ __forceinline__ void pinv(bf16x8& v) { asm volatile("" : "+v"(v)); }

__device__ __forceinline__ u32 AADD(u32* p, u32 v) {
  return __hip_atomic_fetch_add(p, v, __ATOMIC_RELAXED, __HIP_MEMORY_SCOPE_AGENT);
}
__device__ __forceinline__ u32 ALD(const u32* p) {
  return __hip_atomic_load(p, __ATOMIC_RELAXED, __HIP_MEMORY_SCOPE_AGENT);
}
__device__ __forceinline__ u64 ALD64(const u64* p) {
  return __hip_atomic_load(p, __ATOMIC_RELAXED, __HIP_MEMORY_SCOPE_AGENT);
}
__device__ __forceinline__ void AST(u32* p, u32 v) {
  __hip_atomic_store(p, v, __ATOMIC_RELAXED, __HIP_MEMORY_SCOPE_AGENT);
}

// --- prep: Whi[n][k] = bf16(W[k][n]) ----------------------------------------
__global__ void prep_w(const float* __restrict__ W, u16* __restrict__ whi) {
  int n = blockIdx.y;
  int k = blockIdx.x * 256 + threadIdx.x;
  whi[n * 1024 + k] = f2bf(W[k * 1024 + n]);
}

// --- prep: U[t][b][n] = sum_j xt[b][t][j] * Wi[n][j]  (fp32) ---------------
__global__ void prep_u(const float* __restrict__ x, const float* __restrict__ Wi,
                       float* __restrict__ U) {
  __shared__ float wi_t[256][64];
  __shared__ float xt[32][256];
  const int b = blockIdx.x, nt = blockIdx.y, tid = threadIdx.x;
  {
    int n = tid >> 2, jc = (tid & 3) * 64;
    const float* src = Wi + (size_t)(nt * 64 + n) * 256 + jc;
#pragma unroll
    for (int i = 0; i < 64; i += 4) {
      float4 v = *(const float4*)(src + i);
      wi_t[jc + i + 0][n] = v.x; wi_t[jc + i + 1][n] = v.y;
      wi_t[jc + i + 2][n] = v.z; wi_t[jc + i + 3][n] = v.w;
    }
  }
  const int wv = tid >> 6, nn = tid & 63;
  for (int tc = 0; tc < 16; ++tc) {
    __syncthreads();
    for (int s = 0; s < 8; ++s) {
      int fi = s * 256 + tid;
      int tt = fi >> 6, j4 = (fi & 63) * 4;
      int c = j4 >> 6, i = j4 & 63;
      float4 v = *(const float4*)(x + ((size_t)((b * 4 + c) * 512) + tc * 32 + tt) * 64 + i);
      *(float4*)&xt[tt][j4] = v;
    }
    __syncthreads();
    float acc[8] = {0,0,0,0,0,0,0,0};
    for (int j4 = 0; j4 < 64; ++j4) {
      float w0 = wi_t[j4 * 4 + 0][nn], w1 = wi_t[j4 * 4 + 1][nn];
      float w2 = wi_t[j4 * 4 + 2][nn], w3 = wi_t[j4 * 4 + 3][nn];
#pragma unroll
      for (int tt = 0; tt < 8; ++tt) {
        float4 xv = *(const float4*)&xt[wv * 8 + tt][j4 * 4];
        acc[tt] += xv.x * w0 + xv.y * w1 + xv.z * w2 + xv.w * w3;
      }
    }
#pragma unroll
    for (int tt = 0; tt < 8; ++tt)
      U[((size_t)(tc * 32 + wv * 8 + tt) * 32 + b) * 1024 + nt * 64 + nn] = acc[tt];
  }
}

// --- the scan ---------------------------------------------------------------
__global__ void __launch_bounds__(TPB, 1) esn_scan(
    const u16* __restrict__ Whi, const float* __restrict__ U,
    u16* __restrict__ Hb, float* __restrict__ out, u32* __restrict__ bar) {
  __shared__ __align__(16) float red[8 * 64 * 4];   // 8 KB
  __shared__ int sh_q, sh_j, sh_loc;

  const int tid = threadIdx.x;
  const int wv = tid >> 6, lane = tid & 63;
  const int mcol = lane & 15, kb = lane >> 4;

  // ---- census + role claim -------------------------------------------------
  if (tid == 0) {
    int xcd;
    asm volatile("s_getreg_b32 %0, hwreg(HW_REG_XCC_ID)" : "=s"(xcd));
    xcd &= 7;
    AADD(bar + xcd * 64, 1u);
    AADD(bar + 512, 1u);
    while (ALD(bar + 512) < (u32)NWG) __builtin_amdgcn_s_sleep(2);
    bool uni = true;
    for (int k = 0; k < 8; ++k) uni &= (ALD(bar + k * 64) == 32u);
    if (uni) {
      sh_q = xcd;
      sh_j = (int)AADD(bar + (9 + xcd) * 64, 1u);
      sh_loc = 1;
    } else {
      sh_q = blockIdx.x & 7;
      sh_j = blockIdx.x >> 3;
      sh_loc = 0;
    }
  }
  __syncthreads();
  const int q = sh_q, j = sh_j;
  const bool xlocal = (sh_loc != 0);
  const int r0 = q << 4, c0 = j << 5;

  // ---- W fragments: [ntile 2][kt 8] = 64 VGPRs, pinned --------------------
  bf16x8 bh[2][8];
#pragma unroll
  for (int nt = 0; nt < 2; ++nt) {
    const char* wb = (const char*)Whi + (size_t)(c0 + nt * 16 + mcol) * 2048
                     + wv * 512 + kb * 16;
#pragma unroll
    for (int kt = 0; kt < 8; ++kt)
      bh[nt][kt] = *(const bf16x8*)(wb + kt * 64);
  }
#pragma unroll
  for (int nt = 0; nt < 2; ++nt)
#pragma unroll
    for (int kt = 0; kt < 8; ++kt) pinv(bh[nt][kt]);

  // ---- per-thread output mapping ------------------------------------------
  const int row_l = tid >> 4;               // 0..15
  const int col0  = (tid & 15) * 2;         // 0..30
  const int grow  = r0 + row_l;
  const int ont   = col0 >> 4, oci = col0 & 15;
  const int okb   = row_l >> 2, orr = row_l & 3;
  u32* flags = bar + 2048 + q * 64;         // one 128B line per group

  float hreg[2] = {0.f, 0.f};
  f32x2 uf = *(const f32x2*)(U + (size_t)(grow >> 2) * 1024 + c0 + col0);

  for (int t = 0; t < T_STEPS; ++t) {
    // ---- A-fragments of h ---------------------------------------------------
    const char* hsrc = (const char*)Hb + (size_t)(t & 1) * HB_BYTES
                       + (size_t)(r0 + mcol) * 2048 + wv * 512 + kb * 16;
    bf16x8 av[8];
    if (xlocal) {
#pragma unroll
      for (int kt = 0; kt < 8; ++kt)
        av[kt] = *(const bf16x8*)(hsrc + kt * 64);    // plain: L2-local, dedup
    } else {
#pragma unroll
      for (int kt = 0; kt < 8; ++kt) {
        u64x2 p;
        p.x = ALD64((const u64*)(hsrc + kt * 64));
        p.y = ALD64((const u64*)(hsrc + kt * 64 + 8));
        av[kt] = __builtin_bit_cast(bf16x8, p);
      }
    }

    // ---- z = h @ W ----------------------------------------------------------
    f32x4 acc0 = {0.f, 0.f, 0.f, 0.f};
    f32x4 acc1 = {0.f, 0.f, 0.f, 0.f};
#pragma unroll
    for (int kt = 0; kt < 8; ++kt) {
      acc0 = __builtin_amdgcn_mfma_f32_16x16x32_bf16(av[kt], bh[0][kt], acc0, 0, 0, 0);
      acc1 = __builtin_amdgcn_mfma_f32_16x16x32_bf16(av[kt], bh[1][kt], acc1, 0, 0, 0);
    }

    // ---- cross-wave K reduction via LDS ------------------------------------
    *(f32x4*)&red[((wv * 2 + 0) * 64 + lane) * 4] = acc0;
    *(f32x4*)&red[((wv * 2 + 1) * 64 + lane) * 4] = acc1;
    __syncthreads();

    // ---- epilogue -----------------------------------------------------------
    float z0 = 0.f, z1 = 0.f;
#pragma unroll
    for (int w = 0; w < 4; ++w) {
      z0 += red[((w * 2 + ont) * 64 + okb * 16 + oci + 0) * 4 + orr];
      z1 += red[((w * 2 + ont) * 64 + okb * 16 + oci + 1) * 4 + orr];
    }
    float hn0 = 0.5f * tanhf(z0 + uf.x) + 0.5f * hreg[0];
    float hn1 = 0.5f * tanhf(z1 + uf.y) + 0.5f * hreg[1];
    hreg[0] = hn0; hreg[1] = hn1;

    // ---- h store ------------------------------------------------------------
    {
      u32 pk = (u32)f2bf(hn0) | ((u32)f2bf(hn1) << 16);
      u32* hdst = (u32*)((char*)Hb + (size_t)((t + 1) & 1) * HB_BYTES
                         + (size_t)grow * 2048 + (c0 + col0) * 2);
      if (xlocal) {
        *hdst = pk;                                   // plain: acks at local L2
      } else {
        (void)__hip_atomic_exchange(hdst, pk, __ATOMIC_RELAXED,
                                    __HIP_MEMORY_SCOPE_AGENT);
      }
    }
    asm volatile("s_waitcnt vmcnt(0)" ::: "memory");  // h committed (L2 or L3)
    __syncthreads();

    if (t < T_STEPS - 1) {
      if (tid == 0) {
        if (xlocal) *(volatile u32*)(flags + j) = (u32)(t + 1);
        else        AST(flags + j, (u32)(t + 1));
      }
    }

    // out[] full-line nt-store (overlaps poll) + U[t+1] prefetch
    {
      f32x2 o2; o2.x = hn0; o2.y = hn1;
      __builtin_nontemporal_store(o2,
          (f32x2*)(out + ((size_t)grow * 512 + t) * 1024 + c0 + col0));
    }
    if (t < T_STEPS - 1) {
      uf = *(const f32x2*)(U + ((size_t)(t + 1) * 32 + (grow >> 2)) * 1024 + c0 + col0);
      // ---- poll the group's flag line (wave 0 only) ------------------------
      if (wv == 0) {
        u32 tgt = (u32)(t + 1);
        if (xlocal) {
          volatile const u32* f = (volatile const u32*)flags;
          while (true) {
            asm volatile("buffer_inv" ::: "memory");  // L1-only, per-CU
            u32 v = f[lane & 31];
            if (__all(v >= tgt)) break;
            __builtin_amdgcn_s_sleep(1);
          }
        } else {
          while (true) {
            u32 v = ALD(flags + (lane & 31));
            if (__all(v >= tgt)) break;
            __builtin_amdgcn_s_sleep(1);
          }
        }
      }
      __syncthreads();
    }
  }
}

// ============================================================================
extern "C" void kernel_launch(void* const* d_in, const int* in_sizes, int n_in,
                              void* d_out, int out_size, void* d_ws, size_t ws_size,
                              hipStream_t stream) {
  (void)in_sizes; (void)n_in; (void)out_size; (void)ws_size;
  const float* x  = (const float*)d_in[0];   // [32,4,512,64]
  const float* Wi = (const float*)d_in[1];   // [1024,256]
  const float* W  = (const float*)d_in[2];   // [1024,1024]
  float* out = (float*)d_out;                // [32,4,512,1024]

  char* ws  = (char*)d_ws;
  u16*  whi = (u16*)(ws + OFF_WHI);
  float* U  = (float*)(ws + OFF_U);
  u16*  hb  = (u16*)(ws + OFF_HB);
  u32*  bar = (u32*)(ws + OFF_BAR);

  // zero h0 double-buffer + census/claim/flag region (monotonic per launch)
  (void)hipMemsetAsync(ws + OFF_HB, 0, 2 * HB_BYTES + 16384, stream);

  hipLaunchKernelGGL(prep_w, dim3(4, 1024), dim3(256), 0, stream, W, whi);
  hipLaunchKernelGGL(prep_u, dim3(32, 16), dim3(256), 0, stream, x, Wi, U);
  hipLaunchKernelGGL(esn_scan, dim3(NWG), dim3(TPB), 0, stream,
                     whi, U, hb, out, bar);
}

// Round 11
// 1419.375 us; speedup vs baseline: 6.4816x; 1.1905x over previous
//
#include <hip/hip_runtime.h>
#include <hip/hip_bf16.h>
#include <cstdint>
#include <cstddef>

// ============================================================================
// EchoStateNetwork: h_{t+1} = 0.5*tanh(h_t @ W + U[t]) + 0.5*h_t
// U precomputed via 3-term bf16 MFMA GEMM (prep_u2). Persistent 256-WG scan,
// 8 independent row-groups, XCD-local protocol (R9-proven):
//   group g -> XCD g (32 WGs, census+claim). h exchange + flags in local L2.
// R11: poll = tight spin of agent atomic loads (sc1, L1-bypass — the proven
//   primitive; R10's hand-rolled sc0 asm read stale L1 forever -> hang).
//   No per-iteration buffer_inv, no s_sleep; ONE buffer_inv after success
//   (covers the plain h-loads' stale-parity lines). Fallback = R8 L3 protocol.
//
// ws layout:
//   Whi [1024 n][1024 k] bf16                                   2 MB
//   U   [512 t][32 b][1024 n] f32                              64 MB
//   Hb2 [2][128 row][1024 col] bf16                           512 KB
//   bar census[8]/cb/claim[8] (256B apart) + flag lines        16 KB
// ============================================================================

typedef unsigned short u16;
typedef unsigned int   u32;
typedef unsigned long long u64;
typedef __bf16 bf16x8 __attribute__((ext_vector_type(8)));
typedef u64    u64x2  __attribute__((ext_vector_type(2)));
typedef float  f32x4  __attribute__((ext_vector_type(4)));
typedef float  f32x2  __attribute__((ext_vector_type(2)));

#define T_STEPS 512
#define NWG     256
#define TPB     256

#define OFF_WHI 0
#define OFF_U   (2*1024*1024)
#define OFF_HB  (OFF_U + (size_t)512*32*1024*4)
#define HB_BYTES ((size_t)128*2048)             // 256 KB per buffer
#define OFF_BAR (OFF_HB + 2*HB_BYTES)
// bar (u32 idx): census[x]=x*64, cb=512, claim[x]=(9+x)*64, flags[g]=2048+g*64

__device__ __forceinline__ u16 f2bf(float f) {
  u32 u = __builtin_bit_cast(u32, f);
  u += 0x7fffu + ((u >> 16) & 1u);          // RNE
  return (u16)(u >> 16);
}
__device__ __forceinline__ float bf2f(u16 h) {
  u32 u = ((u32)h) << 16;
  return __builtin_bit_cast(float, u);
}
__device__ __forceinline__ void pinv(bf16x8& v) { asm volatile("" : "+v"(v)); }

__device__ __forceinline__ u32 AADD(u32* p, u32 v) {
  return __hip_atomic_fetch_add(p, v, __ATOMIC_RELAXED, __HIP_MEMORY_SCOPE_AGENT);
}
__device__ __forceinline__ u32 ALD(const u32* p) {
  return __hip_atomic_load(p, __ATOMIC_RELAXED, __HIP_MEMORY_SCOPE_AGENT);
}
__device__ __forceinline__ u64 ALD64(const u64* p) {
  return __hip_atomic_load(p, __ATOMIC_RELAXED, __HIP_MEMORY_SCOPE_AGENT);
}
__device__ __forceinline__ void AST(u32* p, u32 v) {
  __hip_atomic_store(p, v, __ATOMIC_RELAXED, __HIP_MEMORY_SCOPE_AGENT);
}

// --- prep: Whi[n][k] = bf16(W[k][n]) ----------------------------------------
__global__ void prep_w(const float* __restrict__ W, u16* __restrict__ whi) {
  int n = blockIdx.y;
  int k = blockIdx.x * 256 + threadIdx.x;
  whi[n * 1024 + k] = f2bf(W[k * 1024 + n]);
}

// --- prep_u2: U[m=t*32+b][n] = sum_k A[m][k]*Wi[n][k], 3-term bf16 MFMA ----
// A[m][k] = x[b][k>>6][t][k&63].  Block: 128m x 128n, K in 2 LDS-staged halves.
__global__ void __launch_bounds__(256) prep_u2(const float* __restrict__ x,
                                               const float* __restrict__ Wi,
                                               float* __restrict__ U) {
  __shared__ __align__(16) u16 Ah[128 * 128];   // 32 KB, XOR-swizzled
  __shared__ __align__(16) u16 Al[128 * 128];   // 32 KB
  const int tid = threadIdx.x;
  const int m0 = blockIdx.x << 7;               // 0..16256
  const int n0 = blockIdx.y << 7;               // 0..896
  const int wv = tid >> 6, lane = tid & 63;
  const int fc = lane & 15, kb = lane >> 4;     // frag lane decomp

  f32x4 acc[8][2];
#pragma unroll
  for (int mt = 0; mt < 8; ++mt) {
    acc[mt][0] = (f32x4){0.f, 0.f, 0.f, 0.f};
    acc[mt][1] = (f32x4){0.f, 0.f, 0.f, 0.f};
  }

  for (int hf = 0; hf < 2; ++hf) {
    __syncthreads();   // protect LDS from previous half's readers
    // ---- stage A half (rows m0..+128, k hf*128..+128) as hi/lo bf16 -------
#pragma unroll
    for (int s = 0; s < 16; ++s) {
      int f = (s << 8) + tid;                   // 0..4095
      int row = f >> 5, v = f & 31;
      int cl = v >> 4, i4 = (v & 15) << 2;
      int b = row & 31, t = (m0 + row) >> 5;    // m0%32==0
      float4 xv = *(const float4*)(x +
          ((size_t)((b << 2) | ((hf << 1) | cl)) * 512 + t) * 64 + i4);
      int byte = (row << 8) + (((cl << 7) + (i4 << 1)) ^ ((row & 7) << 4));
      u16* ph = (u16*)((char*)Ah + byte);
      u16* pl = (u16*)((char*)Al + byte);
      float vv[4] = {xv.x, xv.y, xv.z, xv.w};
#pragma unroll
      for (int e = 0; e < 4; ++e) {
        u16 hh = f2bf(vv[e]);
        ph[e] = hh;
        pl[e] = f2bf(vv[e] - bf2f(hh));
      }
    }
    // ---- B fragments (registers) for this half ----------------------------
    bf16x8 Bh[2][4], Bl[2][4];
#pragma unroll
    for (int nt = 0; nt < 2; ++nt) {
      const float* wrow = Wi + (size_t)(n0 + (wv << 5) + (nt << 4) + fc) * 256;
#pragma unroll
      for (int kt = 0; kt < 4; ++kt) {
        int k = (hf << 7) + (kt << 5) + (kb << 3);
        float tmp[8];
        *(float4*)&tmp[0] = *(const float4*)(wrow + k);
        *(float4*)&tmp[4] = *(const float4*)(wrow + k + 4);
#pragma unroll
        for (int e = 0; e < 8; ++e) {
          u16 hh = f2bf(tmp[e]);
          Bh[nt][kt][e] = __builtin_bit_cast(__bf16, hh);
          Bl[nt][kt][e] = __builtin_bit_cast(__bf16, f2bf(tmp[e] - bf2f(hh)));
        }
      }
    }
    __syncthreads();
    // ---- MFMA: 4kt x 8mt x 2nt x 3 terms ----------------------------------
#pragma unroll
    for (int kt = 0; kt < 4; ++kt) {
      int kbyte = (kt << 6) + (kb << 4);
#pragma unroll
      for (int mt = 0; mt < 8; ++mt) {
        int row = (mt << 4) + fc;
        int byte = (row << 8) + (kbyte ^ ((row & 7) << 4));
        bf16x8 ah = *(const bf16x8*)((char*)Ah + byte);
        bf16x8 al = *(const bf16x8*)((char*)Al + byte);
#pragma unroll
        for (int nt = 0; nt < 2; ++nt) {
          acc[mt][nt] = __builtin_amdgcn_mfma_f32_16x16x32_bf16(ah, Bh[nt][kt], acc[mt][nt], 0, 0, 0);
          acc[mt][nt] = __builtin_amdgcn_mfma_f32_16x16x32_bf16(al, Bh[nt][kt], acc[mt][nt], 0, 0, 0);
          acc[mt][nt] = __builtin_amdgcn_mfma_f32_16x16x32_bf16(ah, Bl[nt][kt], acc[mt][nt], 0, 0, 0);
        }
      }
    }
  }
  // ---- write U: D[row=kb*4+r][col=fc] -------------------------------------
#pragma unroll
  for (int mt = 0; mt < 8; ++mt) {
    int mbase = m0 + (mt << 4) + (kb << 2);
    int n = n0 + (wv << 5) + fc;
#pragma unroll
    for (int nt = 0; nt < 2; ++nt)
#pragma unroll
      for (int r = 0; r < 4; ++r)
        U[(size_t)(mbase + r) * 1024 + n + (nt << 4)] = acc[mt][nt][r];
  }
}

// --- the scan ---------------------------------------------------------------
__global__ void __launch_bounds__(TPB, 1) esn_scan(
    const u16* __restrict__ Whi, const float* __restrict__ U,
    u16* __restrict__ Hb, float* __restrict__ out, u32* __restrict__ bar) {
  __shared__ __align__(16) float red[8 * 64 * 4];   // 8 KB
  __shared__ int sh_q, sh_j, sh_loc;

  const int tid = threadIdx.x;
  const int wv = tid >> 6, lane = tid & 63;
  const int mcol = lane & 15, kb = lane >> 4;

  // ---- census + role claim -------------------------------------------------
  if (tid == 0) {
    int xcd;
    asm volatile("s_getreg_b32 %0, hwreg(HW_REG_XCC_ID)" : "=s"(xcd));
    xcd &= 7;
    AADD(bar + xcd * 64, 1u);
    AADD(bar + 512, 1u);
    while (ALD(bar + 512) < (u32)NWG) __builtin_amdgcn_s_sleep(2);
    bool uni = true;
    for (int k = 0; k < 8; ++k) uni &= (ALD(bar + k * 64) == 32u);
    if (uni) {
      sh_q = xcd;
      sh_j = (int)AADD(bar + (9 + xcd) * 64, 1u);
      sh_loc = 1;
    } else {
      sh_q = blockIdx.x & 7;
      sh_j = blockIdx.x >> 3;
      sh_loc = 0;
    }
  }
  __syncthreads();
  const int q = sh_q, j = sh_j;
  const bool xlocal = (sh_loc != 0);
  const int r0 = q << 4, c0 = j << 5;

  // ---- W fragments: [ntile 2][kt 8] = 64 VGPRs, pinned --------------------
  bf16x8 bh[2][8];
#pragma unroll
  for (int nt = 0; nt < 2; ++nt) {
    const char* wb = (const char*)Whi + (size_t)(c0 + nt * 16 + mcol) * 2048
                     + wv * 512 + kb * 16;
#pragma unroll
    for (int kt = 0; kt < 8; ++kt)
      bh[nt][kt] = *(const bf16x8*)(wb + kt * 64);
  }
#pragma unroll
  for (int nt = 0; nt < 2; ++nt)
#pragma unroll
    for (int kt = 0; kt < 8; ++kt) pinv(bh[nt][kt]);

  // ---- per-thread output mapping ------------------------------------------
  const int row_l = tid >> 4;               // 0..15
  const int col0  = (tid & 15) * 2;         // 0..30
  const int grow  = r0 + row_l;
  const int ont   = col0 >> 4, oci = col0 & 15;
  const int okb   = row_l >> 2, orr = row_l & 3;
  u32* flags = bar + 2048 + q * 64;         // one 128B line per group

  float hreg[2] = {0.f, 0.f};
  f32x2 uf = *(const f32x2*)(U + (size_t)(grow >> 2) * 1024 + c0 + col0);

  for (int t = 0; t < T_STEPS; ++t) {
    // ---- A-fragments of h ---------------------------------------------------
    const char* hsrc = (const char*)Hb + (size_t)(t & 1) * HB_BYTES
                       + (size_t)(r0 + mcol) * 2048 + wv * 512 + kb * 16;
    bf16x8 av[8];
    if (xlocal) {
#pragma unroll
      for (int kt = 0; kt < 8; ++kt)
        av[kt] = *(const bf16x8*)(hsrc + kt * 64);    // plain: L2-local, dedup
    } else {
#pragma unroll
      for (int kt = 0; kt < 8; ++kt) {
        u64x2 p;
        p.x = ALD64((const u64*)(hsrc + kt * 64));
        p.y = ALD64((const u64*)(hsrc + kt * 64 + 8));
        av[kt] = __builtin_bit_cast(bf16x8, p);
      }
    }

    // ---- z = h @ W ----------------------------------------------------------
    f32x4 acc0 = {0.f, 0.f, 0.f, 0.f};
    f32x4 acc1 = {0.f, 0.f, 0.f, 0.f};
#pragma unroll
    for (int kt = 0; kt < 8; ++kt) {
      acc0 = __builtin_amdgcn_mfma_f32_16x16x32_bf16(av[kt], bh[0][kt], acc0, 0, 0, 0);
      acc1 = __builtin_amdgcn_mfma_f32_16x16x32_bf16(av[kt], bh[1][kt], acc1, 0, 0, 0);
    }

    // ---- cross-wave K reduction via LDS ------------------------------------
    *(f32x4*)&red[((wv * 2 + 0) * 64 + lane) * 4] = acc0;
    *(f32x4*)&red[((wv * 2 + 1) * 64 + lane) * 4] = acc1;
    __syncthreads();

    // ---- epilogue -----------------------------------------------------------
    float z0 = 0.f, z1 = 0.f;
#pragma unroll
    for (int w = 0; w < 4; ++w) {
      z0 += red[((w * 2 + ont) * 64 + okb * 16 + oci + 0) * 4 + orr];
      z1 += red[((w * 2 + ont) * 64 + okb * 16 + oci + 1) * 4 + orr];
    }
    float hn0 = 0.5f * tanhf(z0 + uf.x) + 0.5f * hreg[0];
    float hn1 = 0.5f * tanhf(z1 + uf.y) + 0.5f * hreg[1];
    hreg[0] = hn0; hreg[1] = hn1;

    // ---- h store ------------------------------------------------------------
    {
      u32 pk = (u32)f2bf(hn0) | ((u32)f2bf(hn1) << 16);
      u32* hdst = (u32*)((char*)Hb + (size_t)((t + 1) & 1) * HB_BYTES
                         + (size_t)grow * 2048 + (c0 + col0) * 2);
      if (xlocal) {
        *hdst = pk;                                   // plain: acks at local L2
      } else {
        (void)__hip_atomic_exchange(hdst, pk, __ATOMIC_RELAXED,
                                    __HIP_MEMORY_SCOPE_AGENT);
      }
    }
    asm volatile("s_waitcnt vmcnt(0)" ::: "memory");  // h committed (L2 or L3)
    __syncthreads();

    if (t < T_STEPS - 1) {
      if (tid == 0) {
        if (xlocal) *(volatile u32*)(flags + j) = (u32)(t + 1);
        else        AST(flags + j, (u32)(t + 1));
      }
    }

    // out[] full-line nt-store (overlaps poll) + U[t+1] prefetch
    {
      f32x2 o2; o2.x = hn0; o2.y = hn1;
      __builtin_nontemporal_store(o2,
          (f32x2*)(out + ((size_t)grow * 512 + t) * 1024 + c0 + col0));
    }
    if (t < T_STEPS - 1) {
      uf = *(const f32x2*)(U + ((size_t)(t + 1) * 32 + (grow >> 2)) * 1024 + c0 + col0);
      if (wv == 0) {
        u32 tgt = (u32)(t + 1);
        if (xlocal) {
          // tight spin on agent atomic loads (sc1: L1-bypass, local-L2 hit)
          const u32* fp = flags + (lane & 31);
          while (true) {
            u32 v = ALD(fp);
            if (__all((int)(v >= tgt))) break;
          }
          // one L1 invalidate so next-step plain h-loads can't hit stale parity
          asm volatile("buffer_inv\n\ts_waitcnt vmcnt(0)" ::: "memory");
        } else {
          while (true) {
            u32 v = ALD(flags + (lane & 31));
            if (__all((int)(v >= tgt))) break;
            __builtin_amdgcn_s_sleep(1);
          }
        }
      }
      __syncthreads();
    }
  }
}

// ============================================================================
extern "C" void kernel_launch(void* const* d_in, const int* in_sizes, int n_in,
                              void* d_out, int out_size, void* d_ws, size_t ws_size,
                              hipStream_t stream) {
  (void)in_sizes; (void)n_in; (void)out_size; (void)ws_size;
  const float* x  = (const float*)d_in[0];   // [32,4,512,64]
  const float* Wi = (const float*)d_in[1];   // [1024,256]
  const float* W  = (const float*)d_in[2];   // [1024,1024]
  float* out = (float*)d_out;                // [32,4,512,1024]

  char* ws  = (char*)d_ws;
  u16*  whi = (u16*)(ws + OFF_WHI);
  float* U  = (float*)(ws + OFF_U);
  u16*  hb  = (u16*)(ws + OFF_HB);
  u32*  bar = (u32*)(ws + OFF_BAR);

  // zero h0 double-buffer + census/claim/flag region (monotonic per launch)
  (void)hipMemsetAsync(ws + OFF_HB, 0, 2 * HB_BYTES + 16384, stream);

  hipLaunchKernelGGL(prep_w, dim3(4, 1024), dim3(256), 0, stream, W, whi);
  hipLaunchKernelGGL(prep_u2, dim3(128, 8), dim3(256), 0, stream, x, Wi, U);
  hipLaunchKernelGGL(esn_scan, dim3(NWG), dim3(TPB), 0, stream,
                     whi, U, hb, out, bar);
}